// Round 14
// baseline (127.310 us; speedup 1.0000x reference)
//
#include <hip/hip_runtime.h>
#include <math.h>

// Problem constants: B=4, S=2048, D_IN=1024, D_OUT=1024, E=8, K=2
#define TOKENS 8192
#define DIN    1024
#define DOUT   1024
#define NE     8
#define NWAVES 4096   // 512 blocks x 8 waves; wave w handles tokens w and w+NWAVES

typedef float vf4 __attribute__((ext_vector_type(4)));

// R11 (measured best: 2 sequential rounds/wave, LDS f32 gate, stage-major,
// x-prefetch) with PHASE-INTERLEAVED rounds: round-0's value-row loads are
// issued right after round-0's select, then round-1's whole gate phase runs
// in that load's L2-latency shadow; round-1's value loads are issued before
// round-0's value math consumes its (now arrived) weights. Each round's
// ~200-500-cycle value-load latency is hidden under the other round's
// independent work. Register peak ~115 VGPR < 128 cap (bounds(512,4)).
__global__ __launch_bounds__(512, 4) void moe_fused(
    const float* __restrict__ x,             // [TOKENS][DIN]
    const float* __restrict__ gate_w,        // [NE][DIN]
    const float* __restrict__ gate_b,        // [NE]
    const float* __restrict__ expert_biases, // [NE]
    const float* __restrict__ expert_w,      // [NE][DOUT][DIN]
    const float* __restrict__ expert_b,      // [NE][DOUT]
    float* __restrict__ out,                 // [TOKENS][DOUT]
    float* __restrict__ out_idx) {           // [TOKENS][2] (indices as f32)
  __shared__ float lgate[NE * DIN];  // 32 KB f32 (selection must be f32-exact)

  {
    const vf4* src = (const vf4*)gate_w;
    vf4* dst = (vf4*)lgate;
#pragma unroll
    for (int i = 0; i < 4; ++i)
      dst[threadIdx.x + 512 * i] = src[threadIdx.x + 512 * i];
  }

  const int w    = blockIdx.x * 8 + (threadIdx.x >> 6);
  const int lane = threadIdx.x & 63;
  const int t0 = w;
  const int t1 = w + NWAVES;

  // wave-uniform gate biases, loaded once, reused for both rounds
  float zbias[NE];
#pragma unroll
  for (int e = 0; e < NE; ++e) zbias[e] = gate_b[e] + expert_biases[e];

  // round-0 x issued before the barrier (latency hides under barrier drain)
  vf4 xa[4];
  const vf4* xr0 = (const vf4*)(x + (size_t)t0 * DIN);
#pragma unroll
  for (int i = 0; i < 4; ++i) xa[i] = xr0[lane + 64 * i];

  __syncthreads();

  // ======== round-0 gate ========
  float za[NE];
#pragma unroll
  for (int e = 0; e < NE; ++e) za[e] = 0.f;
#pragma unroll
  for (int i = 0; i < 4; ++i) {
    vf4 wv[NE];
#pragma unroll
    for (int e = 0; e < NE; ++e)
      wv[e] = ((const vf4*)(lgate + e * DIN))[lane + 64 * i];
#pragma unroll
    for (int e = 0; e < NE; ++e)
      za[e] += xa[i].x * wv[e].x + xa[i].y * wv[e].y + xa[i].z * wv[e].z + xa[i].w * wv[e].w;
  }

  // prefetch round-1 x (independent; ~2000 cycles before first use)
  vf4 xb[4];
  const vf4* xr1 = (const vf4*)(x + (size_t)t1 * DIN);
#pragma unroll
  for (int i = 0; i < 4; ++i) xb[i] = xr1[lane + 64 * i];

#pragma unroll
  for (int off = 32; off > 0; off >>= 1) {
    float tmp[NE];
#pragma unroll
    for (int e = 0; e < NE; ++e) tmp[e] = __shfl_xor(za[e], off, 64);
#pragma unroll
    for (int e = 0; e < NE; ++e) za[e] += tmp[e];
  }
#pragma unroll
  for (int e = 0; e < NE; ++e) za[e] += zbias[e];

  int e0 = 0; float z0 = za[0];
#pragma unroll
  for (int e = 1; e < NE; ++e) if (za[e] > z0) { z0 = za[e]; e0 = e; }
  int e1 = (e0 == 0) ? 1 : 0; float z1 = za[e1];
#pragma unroll
  for (int e = 0; e < NE; ++e) if (e != e0 && za[e] > z1) { z1 = za[e]; e1 = e; }

  // ---- ISSUE round-0 value loads now; consume them only after round-1's
  //      gate phase has filled the latency shadow ----
  const vf4* ra0 = (const vf4*)(expert_w + (size_t)e0 * (DOUT * DIN));        // w[e0][0][:]
  const vf4* ra1 = (const vf4*)(expert_w + (size_t)e1 * (DOUT * DIN) + DIN);  // w[e1][1][:]
  vf4 wa[4], wbv[4];
#pragma unroll
  for (int i = 0; i < 4; ++i) { wa[i] = ra0[lane + 64 * i]; wbv[i] = ra1[lane + 64 * i]; }
  float ba0 = expert_b[e0 * DOUT + 0];
  float ba1 = expert_b[e1 * DOUT + 1];

  if (lane == 0) {
    out_idx[t0 * 2 + 0] = (float)e0;
    out_idx[t0 * 2 + 1] = (float)e1;
  }

  // ======== round-1 gate (runs inside round-0's value-load shadow) ========
  float zb[NE];
#pragma unroll
  for (int e = 0; e < NE; ++e) zb[e] = 0.f;
#pragma unroll
  for (int i = 0; i < 4; ++i) {
    vf4 wv[NE];
#pragma unroll
    for (int e = 0; e < NE; ++e)
      wv[e] = ((const vf4*)(lgate + e * DIN))[lane + 64 * i];
#pragma unroll
    for (int e = 0; e < NE; ++e)
      zb[e] += xb[i].x * wv[e].x + xb[i].y * wv[e].y + xb[i].z * wv[e].z + xb[i].w * wv[e].w;
  }
#pragma unroll
  for (int off = 32; off > 0; off >>= 1) {
    float tmp[NE];
#pragma unroll
    for (int e = 0; e < NE; ++e) tmp[e] = __shfl_xor(zb[e], off, 64);
#pragma unroll
    for (int e = 0; e < NE; ++e) zb[e] += tmp[e];
  }
#pragma unroll
  for (int e = 0; e < NE; ++e) zb[e] += zbias[e];

  int f0 = 0; float y0 = zb[0];
#pragma unroll
  for (int e = 1; e < NE; ++e) if (zb[e] > y0) { y0 = zb[e]; f0 = e; }
  int f1 = (f0 == 0) ? 1 : 0; float y1 = zb[f1];
#pragma unroll
  for (int e = 0; e < NE; ++e) if (e != f0 && zb[e] > y1) { y1 = zb[e]; f1 = e; }

  // ---- ISSUE round-1 value loads (their latency hides under round-0's
  //      value math + reduce + store) ----
  const vf4* rb0 = (const vf4*)(expert_w + (size_t)f0 * (DOUT * DIN));
  const vf4* rb1 = (const vf4*)(expert_w + (size_t)f1 * (DOUT * DIN) + DIN);
  vf4 wc[4], wd[4];
#pragma unroll
  for (int i = 0; i < 4; ++i) { wc[i] = rb0[lane + 64 * i]; wd[i] = rb1[lane + 64 * i]; }
  float bb0 = expert_b[f0 * DOUT + 0];
  float bb1 = expert_b[f1 * DOUT + 1];

  if (lane == 0) {
    out_idx[t1 * 2 + 0] = (float)f0;
    out_idx[t1 * 2 + 1] = (float)f1;
  }

  // ======== round-0 value math + store (weights have arrived) ========
  {
    float p0 = 1.f / (1.f + expf(-z0));
    float p1 = 1.f / (1.f + expf(-z1));
    float s  = 1.f / (p0 + p1);
    float w0 = p0 * s, w1 = p1 * s;

    float ovp = 0.f;
#pragma unroll
    for (int i = 0; i < 4; ++i) {
      float d0p = xa[i].x * wa[i].x + xa[i].y * wa[i].y + xa[i].z * wa[i].z + xa[i].w * wa[i].w;
      float d1p = xa[i].x * wbv[i].x + xa[i].y * wbv[i].y + xa[i].z * wbv[i].z + xa[i].w * wbv[i].w;
      ovp += d0p * w0 + d1p * w1;
    }
#pragma unroll
    for (int off = 32; off > 0; off >>= 1) ovp += __shfl_xor(ovp, off, 64);
    float ov = ovp + ba0 * w0 + ba1 * w1;

    vf4 v = {ov, ov, ov, ov};
    vf4* orow = (vf4*)(out + (size_t)t0 * DOUT);
#pragma unroll
    for (int i = 0; i < 4; ++i) orow[lane + 64 * i] = v;  // drains under round-1 value math
  }

  // ======== round-1 value math + store ========
  {
    float p0 = 1.f / (1.f + expf(-y0));
    float p1 = 1.f / (1.f + expf(-y1));
    float s  = 1.f / (p0 + p1);
    float w0 = p0 * s, w1 = p1 * s;

    float ovp = 0.f;
#pragma unroll
    for (int i = 0; i < 4; ++i) {
      float d0p = xb[i].x * wc[i].x + xb[i].y * wc[i].y + xb[i].z * wc[i].z + xb[i].w * wc[i].w;
      float d1p = xb[i].x * wd[i].x + xb[i].y * wd[i].y + xb[i].z * wd[i].z + xb[i].w * wd[i].w;
      ovp += d0p * w0 + d1p * w1;
    }
#pragma unroll
    for (int off = 32; off > 0; off >>= 1) ovp += __shfl_xor(ovp, off, 64);
    float ov = ovp + bb0 * w0 + bb1 * w1;

    vf4 v = {ov, ov, ov, ov};
    vf4* orow = (vf4*)(out + (size_t)t1 * DOUT);
#pragma unroll
    for (int i = 0; i < 4; ++i) orow[lane + 64 * i] = v;
  }
}

extern "C" void kernel_launch(void* const* d_in, const int* in_sizes, int n_in,
                              void* d_out, int out_size, void* d_ws, size_t ws_size,
                              hipStream_t stream) {
  const float* x             = (const float*)d_in[0];
  const float* gate_w        = (const float*)d_in[1];
  const float* gate_b        = (const float*)d_in[2];
  const float* expert_biases = (const float*)d_in[3];
  const float* expert_w      = (const float*)d_in[4];
  const float* expert_b      = (const float*)d_in[5];

  float* out     = (float*)d_out;
  float* out_idx = out + (size_t)TOKENS * DOUT;  // second tuple output, flat-concatenated

  // 512 blocks x 512 threads (8 waves) x 2 sequential tokens/wave = 8192 tokens.
  moe_fused<<<dim3(512), dim3(512), 0, stream>>>(
      x, gate_w, gate_b, expert_biases, expert_w, expert_b, out, out_idx);
}

// Round 15
// 112.274 us; speedup vs baseline: 1.1339x; 1.1339x over previous
//
#include <hip/hip_runtime.h>
#include <math.h>

// Problem constants: B=4, S=2048, D_IN=1024, D_OUT=1024, E=8, K=2
#define TOKENS 8192
#define DIN    1024
#define DOUT   1024
#define NE     8
#define NWAVES 4096   // 512 blocks x 8 waves; each wave does tokens w and w+NWAVES

typedef float vf4 __attribute__((ext_vector_type(4)));

// MEASURED-BEST (R11, 110.6 us bench): 2-round software-pipelined, fused,
// LDS-staged f32 gate, stage-major issue, butterfly gate reduce, round-1 x
// prefetched during round-0 compute. Wider in-flight state (parallel tokens,
// value-load interleave) measured WORSE (register pressure); do not widen.
__global__ __launch_bounds__(512, 4) void moe_fused(
    const float* __restrict__ x,             // [TOKENS][DIN]
    const float* __restrict__ gate_w,        // [NE][DIN]
    const float* __restrict__ gate_b,        // [NE]
    const float* __restrict__ expert_biases, // [NE]
    const float* __restrict__ expert_w,      // [NE][DOUT][DIN]
    const float* __restrict__ expert_b,      // [NE][DOUT]
    float* __restrict__ out,                 // [TOKENS][DOUT]
    float* __restrict__ out_idx) {           // [TOKENS][2] (indices as f32)
  __shared__ float lgate[NE * DIN];  // 32 KB f32 (selection must be f32-exact)

  {
    const vf4* src = (const vf4*)gate_w;
    vf4* dst = (vf4*)lgate;
#pragma unroll
    for (int i = 0; i < 4; ++i)
      dst[threadIdx.x + 512 * i] = src[threadIdx.x + 512 * i];
  }

  const int w    = blockIdx.x * 8 + (threadIdx.x >> 6);
  const int lane = threadIdx.x & 63;
  const int t0 = w;
  const int t1 = w + NWAVES;

  // wave-uniform gate biases, loaded once, reused for both tokens
  float zbias[NE];
#pragma unroll
  for (int e = 0; e < NE; ++e) zbias[e] = gate_b[e] + expert_biases[e];

  // round-0 x issued before the barrier (latency hides under barrier drain)
  vf4 xa[4];
  const vf4* xr0 = (const vf4*)(x + (size_t)t0 * DIN);
#pragma unroll
  for (int i = 0; i < 4; ++i) xa[i] = xr0[lane + 64 * i];

  __syncthreads();

  // ================= round 0: token t0 =================
  float za[NE];
#pragma unroll
  for (int e = 0; e < NE; ++e) za[e] = 0.f;
#pragma unroll
  for (int i = 0; i < 4; ++i) {
    vf4 wv[NE];
#pragma unroll
    for (int e = 0; e < NE; ++e)
      wv[e] = ((const vf4*)(lgate + e * DIN))[lane + 64 * i];
#pragma unroll
    for (int e = 0; e < NE; ++e)
      za[e] += xa[i].x * wv[e].x + xa[i].y * wv[e].y + xa[i].z * wv[e].z + xa[i].w * wv[e].w;
  }

  // ---- prefetch round-1 x NOW: independent, ~2000 cycles before first use ----
  vf4 xb[4];
  const vf4* xr1 = (const vf4*)(x + (size_t)t1 * DIN);
#pragma unroll
  for (int i = 0; i < 4; ++i) xb[i] = xr1[lane + 64 * i];

  // butterfly reduce (stage-major: 8 independent shuffles per stage)
#pragma unroll
  for (int off = 32; off > 0; off >>= 1) {
    float tmp[NE];
#pragma unroll
    for (int e = 0; e < NE; ++e) tmp[e] = __shfl_xor(za[e], off, 64);
#pragma unroll
    for (int e = 0; e < NE; ++e) za[e] += tmp[e];
  }
#pragma unroll
  for (int e = 0; e < NE; ++e) za[e] += zbias[e];

  int e0 = 0; float z0 = za[0];
#pragma unroll
  for (int e = 1; e < NE; ++e) if (za[e] > z0) { z0 = za[e]; e0 = e; }
  int e1 = (e0 == 0) ? 1 : 0; float z1 = za[e1];
#pragma unroll
  for (int e = 0; e < NE; ++e) if (e != e0 && za[e] > z1) { z1 = za[e]; e1 = e; }

  if (lane == 0) {
    out_idx[t0 * 2 + 0] = (float)e0;
    out_idx[t0 * 2 + 1] = (float)e1;
  }

  {
    const vf4* r0 = (const vf4*)(expert_w + (size_t)e0 * (DOUT * DIN));        // w[e0][0][:]
    const vf4* r1 = (const vf4*)(expert_w + (size_t)e1 * (DOUT * DIN) + DIN);  // w[e1][1][:]
    vf4 wa[4], wb[4];
#pragma unroll
    for (int i = 0; i < 4; ++i) { wa[i] = r0[lane + 64 * i]; wb[i] = r1[lane + 64 * i]; }
    float b0 = expert_b[e0 * DOUT + 0];
    float b1 = expert_b[e1 * DOUT + 1];

    float p0 = 1.f / (1.f + expf(-z0));
    float p1 = 1.f / (1.f + expf(-z1));
    float s  = 1.f / (p0 + p1);
    float w0 = p0 * s, w1 = p1 * s;

    // per-lane weighted partial, one butterfly (w0/w1 wave-uniform)
    float ovp = 0.f;
#pragma unroll
    for (int i = 0; i < 4; ++i) {
      float d0p = xa[i].x * wa[i].x + xa[i].y * wa[i].y + xa[i].z * wa[i].z + xa[i].w * wa[i].w;
      float d1p = xa[i].x * wb[i].x + xa[i].y * wb[i].y + xa[i].z * wb[i].z + xa[i].w * wb[i].w;
      ovp += d0p * w0 + d1p * w1;
    }
#pragma unroll
    for (int off = 32; off > 0; off >>= 1) ovp += __shfl_xor(ovp, off, 64);
    float ov = ovp + b0 * w0 + b1 * w1;

    vf4 v = {ov, ov, ov, ov};
    vf4* orow = (vf4*)(out + (size_t)t0 * DOUT);
#pragma unroll
    for (int i = 0; i < 4; ++i) orow[lane + 64 * i] = v;  // drains under round-1 DS work
  }

  // ================= round 1: token t1 (xb already in flight/resident) =================
#pragma unroll
  for (int e = 0; e < NE; ++e) za[e] = 0.f;
#pragma unroll
  for (int i = 0; i < 4; ++i) {
    vf4 wv[NE];
#pragma unroll
    for (int e = 0; e < NE; ++e)
      wv[e] = ((const vf4*)(lgate + e * DIN))[lane + 64 * i];
#pragma unroll
    for (int e = 0; e < NE; ++e)
      za[e] += xb[i].x * wv[e].x + xb[i].y * wv[e].y + xb[i].z * wv[e].z + xb[i].w * wv[e].w;
  }

#pragma unroll
  for (int off = 32; off > 0; off >>= 1) {
    float tmp[NE];
#pragma unroll
    for (int e = 0; e < NE; ++e) tmp[e] = __shfl_xor(za[e], off, 64);
#pragma unroll
    for (int e = 0; e < NE; ++e) za[e] += tmp[e];
  }
#pragma unroll
  for (int e = 0; e < NE; ++e) za[e] += zbias[e];

  int f0 = 0; float y0 = za[0];
#pragma unroll
  for (int e = 1; e < NE; ++e) if (za[e] > y0) { y0 = za[e]; f0 = e; }
  int f1 = (f0 == 0) ? 1 : 0; float y1 = za[f1];
#pragma unroll
  for (int e = 0; e < NE; ++e) if (e != f0 && za[e] > y1) { y1 = za[e]; f1 = e; }

  if (lane == 0) {
    out_idx[t1 * 2 + 0] = (float)f0;
    out_idx[t1 * 2 + 1] = (float)f1;
  }

  {
    const vf4* r0 = (const vf4*)(expert_w + (size_t)f0 * (DOUT * DIN));
    const vf4* r1 = (const vf4*)(expert_w + (size_t)f1 * (DOUT * DIN) + DIN);
    vf4 wa[4], wb[4];
#pragma unroll
    for (int i = 0; i < 4; ++i) { wa[i] = r0[lane + 64 * i]; wb[i] = r1[lane + 64 * i]; }
    float b0 = expert_b[f0 * DOUT + 0];
    float b1 = expert_b[f1 * DOUT + 1];

    float p0 = 1.f / (1.f + expf(-y0));
    float p1 = 1.f / (1.f + expf(-y1));
    float s  = 1.f / (p0 + p1);
    float w0 = p0 * s, w1 = p1 * s;

    float ovp = 0.f;
#pragma unroll
    for (int i = 0; i < 4; ++i) {
      float d0p = xb[i].x * wa[i].x + xb[i].y * wa[i].y + xb[i].z * wa[i].z + xb[i].w * wa[i].w;
      float d1p = xb[i].x * wb[i].x + xb[i].y * wb[i].y + xb[i].z * wb[i].z + xb[i].w * wb[i].w;
      ovp += d0p * w0 + d1p * w1;
    }
#pragma unroll
    for (int off = 32; off > 0; off >>= 1) ovp += __shfl_xor(ovp, off, 64);
    float ov = ovp + b0 * w0 + b1 * w1;

    vf4 v = {ov, ov, ov, ov};
    vf4* orow = (vf4*)(out + (size_t)t1 * DOUT);
#pragma unroll
    for (int i = 0; i < 4; ++i) orow[lane + 64 * i] = v;
  }
}

extern "C" void kernel_launch(void* const* d_in, const int* in_sizes, int n_in,
                              void* d_out, int out_size, void* d_ws, size_t ws_size,
                              hipStream_t stream) {
  const float* x             = (const float*)d_in[0];
  const float* gate_w        = (const float*)d_in[1];
  const float* gate_b        = (const float*)d_in[2];
  const float* expert_biases = (const float*)d_in[3];
  const float* expert_w      = (const float*)d_in[4];
  const float* expert_b      = (const float*)d_in[5];

  float* out     = (float*)d_out;
  float* out_idx = out + (size_t)TOKENS * DOUT;  // second tuple output, flat-concatenated

  // 512 blocks x 512 threads (8 waves) x 2 sequential tokens/wave = 8192 tokens.
  moe_fused<<<dim3(512), dim3(512), 0, stream>>>(
      x, gate_w, gate_b, expert_biases, expert_w, expert_b, out, out_idx);
}